// Round 2
// baseline (201.401 us; speedup 1.0000x reference)
//
#include <hip/hip_runtime.h>
#include <hip/hip_bf16.h>

#define D_DIM 128
#define K_NBR 32
#define NU 4            // nodes per wave-group
#define NWAVES 16       // waves per block
#define TPB (NWAVES * 64)
#define NBLK 512

// d_ws layout: [0, 65536): GT4 bf16, quad-interleaved:
//   element (j,d) at ushort idx ((q*64 + (d>>1))*2 + (d&1))*4 + r,  q=j>>2, r=j&3
//   -> one uint4 per (q, lane) holds G[2l][4q..4q+3] | G[2l+1][4q..4q+3]
// [65536, 66048): fused bias f32[128]

__device__ __forceinline__ float bfu_lo(unsigned int w) {
    union { unsigned int i; float f; } v; v.i = w << 16; return v.f;
}
__device__ __forceinline__ float bfu_hi(unsigned int w) {
    union { unsigned int i; float f; } v; v.i = w & 0xffff0000u; return v.f;
}

// G[d][j] = sum_k Wc[d][k] * (j<128 ? Wn[k][j] : Ws[k][j-128])
// bb[d]   = sum_k Wc[d][k] * (bn[k]+bs[k]) + bc[d]
__global__ void pinsage_precompute(const float* __restrict__ Wn_w, const float* __restrict__ Wn_b,
                                   const float* __restrict__ Ws_w, const float* __restrict__ Ws_b,
                                   const float* __restrict__ Wc_w, const float* __restrict__ Wc_b,
                                   unsigned short* __restrict__ GT4, float* __restrict__ bb) {
    __shared__ float sWc[D_DIM * 129];          // +1-pad: bank = (d+k)&31, conflict-free
    const int d = threadIdx.x;                  // 0..127
    const int b = blockIdx.x;

    // stage Wc coalesced (64 KB, 32 float4 per thread)
    {
        const float4* src = reinterpret_cast<const float4*>(Wc_w);
        #pragma unroll
        for (int i = 0; i < 32; ++i) {
            const float4 v = src[d + i * D_DIM];
            const int e = 4 * (d + i * D_DIM);       // flat float index
            const int r = e >> 7, c0 = e & 127;      // row, col
            float* dst = &sWc[r * 129 + c0];
            dst[0] = v.x; dst[1] = v.y; dst[2] = v.z; dst[3] = v.w;
        }
    }
    __syncthreads();

    if (b < 2 * D_DIM) {
        const int j = b;
        const float* Wsrc = (j < D_DIM) ? Wn_w : Ws_w;
        const int jj = j & (D_DIM - 1);
        float acc = 0.f;
        #pragma unroll 8
        for (int k = 0; k < D_DIM; ++k)
            acc += sWc[d * 129 + k] * Wsrc[k * D_DIM + jj];
        __hip_bfloat16 hb = __float2bfloat16(acc);
        unsigned short us = *reinterpret_cast<unsigned short*>(&hb);
        const int q = j >> 2, r = j & 3;
        GT4[(((q * 64 + (d >> 1)) * 2 + (d & 1)) * 4) + r] = us;
    } else {
        float acc = Wc_b[d];
        #pragma unroll 8
        for (int k = 0; k < D_DIM; ++k)
            acc += sWc[d * 129 + k] * (Wn_b[k] + Ws_b[k]);
        bb[d] = acc;
    }
}

__global__ __launch_bounds__(TPB, 8) void pinsage_main(
    const int* __restrict__ node_ids,
    const float* __restrict__ emb,
    const int* __restrict__ nbr_ids,
    const float* __restrict__ nbr_w,
    const unsigned short* __restrict__ GT4,
    const float* __restrict__ bbg,
    float* __restrict__ out,
    int B) {

    __shared__ float sU[NWAVES][NU][2 * D_DIM];         // 64 KB per-wave [weighted|x_self]
    __shared__ int   sId[NWAVES][NU][K_NBR];            // 8 KB
    __shared__ float sW[NWAVES][NU][K_NBR];             // 8 KB   total 80 KB -> 2 blocks/CU

    const int tid = threadIdx.x;
    const int wave = tid >> 6;
    const int lane = tid & 63;
    const int h = lane >> 5;   // half-wave
    const int c = lane & 31;

    const float2 bbv = *reinterpret_cast<const float2*>(&bbg[2 * lane]);  // dims 2l,2l+1
    const uint4* Gp = reinterpret_cast<const uint4*>(GT4) + lane;

    const int nGroups = (B + NU - 1) / NU;
    const int gstride = gridDim.x * NWAVES;

    for (int g = blockIdx.x * NWAVES + wave; g < nGroups; g += gstride) {
        const int base = g * NU;

        // ---- Phase A: neighbor ids/weights + self embedding (coalesced) ----
        #pragma unroll
        for (int p = 0; p < 2; ++p) {
            const int i = 2 * p + h;                 // half-wave h handles nodes h, 2+h
            const int n = base + i;
            const int nid = (n < B) ? node_ids[n] : 0;
            const size_t rb = (size_t)nid * K_NBR;
            sId[wave][i][c] = nbr_ids[rb + c];
            sW[wave][i][c]  = nbr_w[rb + c];
            const float4 xs = reinterpret_cast<const float4*>(emb + (size_t)nid * D_DIM)[c];
            *reinterpret_cast<float4*>(&sU[wave][i][D_DIM + 4 * c]) = xs;
        }

        // ---- Phase B: weighted neighbor reduction (random 512B row gathers) ----
        #pragma unroll
        for (int p = 0; p < 2; ++p) {
            const int i = 2 * p + h;
            float4 a0 = make_float4(0.f, 0.f, 0.f, 0.f);
            float4 a1 = make_float4(0.f, 0.f, 0.f, 0.f);
            for (int k = 0; k < K_NBR; k += 4) {
                const int id0 = sId[wave][i][k];
                const int id1 = sId[wave][i][k + 1];
                const int id2 = sId[wave][i][k + 2];
                const int id3 = sId[wave][i][k + 3];
                const float w0 = sW[wave][i][k];
                const float w1 = sW[wave][i][k + 1];
                const float w2 = sW[wave][i][k + 2];
                const float w3 = sW[wave][i][k + 3];
                const float4 r0 = reinterpret_cast<const float4*>(emb + (size_t)id0 * D_DIM)[c];
                const float4 r1 = reinterpret_cast<const float4*>(emb + (size_t)id1 * D_DIM)[c];
                const float4 r2 = reinterpret_cast<const float4*>(emb + (size_t)id2 * D_DIM)[c];
                const float4 r3 = reinterpret_cast<const float4*>(emb + (size_t)id3 * D_DIM)[c];
                a0.x = fmaf(w0, r0.x, a0.x); a0.y = fmaf(w0, r0.y, a0.y);
                a0.z = fmaf(w0, r0.z, a0.z); a0.w = fmaf(w0, r0.w, a0.w);
                a1.x = fmaf(w1, r1.x, a1.x); a1.y = fmaf(w1, r1.y, a1.y);
                a1.z = fmaf(w1, r1.z, a1.z); a1.w = fmaf(w1, r1.w, a1.w);
                a0.x = fmaf(w2, r2.x, a0.x); a0.y = fmaf(w2, r2.y, a0.y);
                a0.z = fmaf(w2, r2.z, a0.z); a0.w = fmaf(w2, r2.w, a0.w);
                a1.x = fmaf(w3, r3.x, a1.x); a1.y = fmaf(w3, r3.y, a1.y);
                a1.z = fmaf(w3, r3.z, a1.z); a1.w = fmaf(w3, r3.w, a1.w);
            }
            a0.x += a1.x; a0.y += a1.y; a0.z += a1.z; a0.w += a1.w;
            *reinterpret_cast<float4*>(&sU[wave][i][4 * c]) = a0;
        }

        // ---- Phase C: fused GEMM  z[d] = relu(sum_j G[d][j]*u[j] + bb[d]) ----
        // lane owns dims d0=2l, d1=2l+1; G streamed from L2 (resident, 64 KB)
        float acc[NU][2];
        #pragma unroll
        for (int n = 0; n < NU; ++n) { acc[n][0] = 0.f; acc[n][1] = 0.f; }

        #pragma unroll 2
        for (int q = 0; q < 64; ++q) {
            const uint4 gw = Gp[q * 64];   // G[d0][4q..4q+3] | G[d1][4q..4q+3]
            const float g00 = bfu_lo(gw.x), g01 = bfu_hi(gw.x);
            const float g02 = bfu_lo(gw.y), g03 = bfu_hi(gw.y);
            const float g10 = bfu_lo(gw.z), g11 = bfu_hi(gw.z);
            const float g12 = bfu_lo(gw.w), g13 = bfu_hi(gw.w);
            #pragma unroll
            for (int n = 0; n < NU; ++n) {
                const float4 uu = *reinterpret_cast<const float4*>(&sU[wave][n][4 * q]); // broadcast
                acc[n][0] = fmaf(g00, uu.x, fmaf(g01, uu.y, fmaf(g02, uu.z, fmaf(g03, uu.w, acc[n][0]))));
                acc[n][1] = fmaf(g10, uu.x, fmaf(g11, uu.y, fmaf(g12, uu.z, fmaf(g13, uu.w, acc[n][1]))));
            }
        }

        // ---- epilogue: bias + relu + coalesced store ----
        #pragma unroll
        for (int n = 0; n < NU; ++n) {
            const int node = base + n;
            if (node < B) {
                float2 r;
                r.x = fmaxf(acc[n][0] + bbv.x, 0.f);
                r.y = fmaxf(acc[n][1] + bbv.y, 0.f);
                *reinterpret_cast<float2*>(&out[(size_t)node * D_DIM + 2 * lane]) = r;
            }
        }
    }
}

extern "C" void kernel_launch(void* const* d_in, const int* in_sizes, int n_in,
                              void* d_out, int out_size, void* d_ws, size_t ws_size,
                              hipStream_t stream) {
    const int*   node_ids = (const int*)  d_in[0];
    const float* emb      = (const float*)d_in[1];
    const int*   nbr_ids  = (const int*)  d_in[2];
    const float* nbr_w    = (const float*)d_in[3];
    const float* Wn_w     = (const float*)d_in[4];
    const float* Wn_b     = (const float*)d_in[5];
    const float* Ws_w     = (const float*)d_in[6];
    const float* Ws_b     = (const float*)d_in[7];
    const float* Wc_w     = (const float*)d_in[8];
    const float* Wc_b     = (const float*)d_in[9];
    const int B = in_sizes[0];

    unsigned short* GT4 = (unsigned short*)d_ws;
    float* bb = (float*)((char*)d_ws + 65536);
    float* out = (float*)d_out;

    pinsage_precompute<<<2 * D_DIM + 1, D_DIM, 0, stream>>>(Wn_w, Wn_b, Ws_w, Ws_b, Wc_w, Wc_b, GT4, bb);
    pinsage_main<<<NBLK, TPB, 0, stream>>>(node_ids, emb, nbr_ids, nbr_w, GT4, bb, out, B);
}